// Round 2
// baseline (2031.452 us; speedup 1.0000x reference)
//
#include <hip/hip_runtime.h>
#include <stdint.h>

typedef unsigned int u32;

#define CIN   16
#define COUT  32
#define NKER  64
#define KEYSPACE 262144   // 64^3
#define KEYMASK  0x3FFFFu

// ---------------------------------------------------------------------------
// Pass 1: per-point key/kidx computation, presence marking, kidx histogram
// ---------------------------------------------------------------------------
__global__ __launch_bounds__(256) void k_pass1(
    const int4* __restrict__ coords, const int* __restrict__ dstride,
    u32* __restrict__ keyPacked, u32* __restrict__ presence,
    u32* __restrict__ hist, int n)
{
    __shared__ u32 lh[NKER];
    int tid = threadIdx.x;
    if (tid < NKER) lh[tid] = 0;
    __syncthreads();
    int i = blockIdx.x * 256 + tid;
    if (i < n) {
        int4 c = coords[i];
        int s = dstride[0];
        u32 kid = (u32)(c.y / s);
        u32 key = ((u32)c.x << 12) | ((u32)c.z << 6) | (u32)c.w;
        keyPacked[i] = key | (kid << 18);
        presence[key] = 1u;
        atomicAdd(&lh[kid], 1u);
    }
    __syncthreads();
    if (tid < NKER && lh[tid]) atomicAdd(&hist[tid], lh[tid]);
}

// ---------------------------------------------------------------------------
// Tiny single-thread scan over 64 bins: aligned bin starts -> cursor init
// (each bin padded to a multiple of 64 so every wave sees a uniform kidx)
// ---------------------------------------------------------------------------
__global__ void k_binscan(const u32* __restrict__ hist, u32* __restrict__ cursor)
{
    if (threadIdx.x == 0 && blockIdx.x == 0) {
        u32 s = 0;
        for (int k = 0; k < NKER; k++) {
            cursor[k * 32] = s;           // cursors padded 128B apart
            u32 h = hist[k];
            s += (h + 63u) & ~63u;
        }
    }
}

// ---------------------------------------------------------------------------
// Pass 2: scatter point indices into kidx bins (block-aggregated cursors)
// ---------------------------------------------------------------------------
__global__ __launch_bounds__(256) void k_scatter(
    const u32* __restrict__ keyPacked, u32* __restrict__ cursor,
    u32* __restrict__ binIdx, int n)
{
    __shared__ u32 lh[NKER];
    __shared__ u32 lbase[NKER];
    int tid = threadIdx.x;
    if (tid < NKER) lh[tid] = 0;
    __syncthreads();
    int i = blockIdx.x * 256 + tid;
    u32 kid = 0, pos = 0;
    bool v = i < n;
    if (v) {
        kid = keyPacked[i] >> 18;
        pos = atomicAdd(&lh[kid], 1u);
    }
    __syncthreads();
    if (tid < NKER && lh[tid]) lbase[tid] = atomicAdd(&cursor[tid * 32], lh[tid]);
    __syncthreads();
    if (v) binIdx[lbase[kid] + pos] = i;
}

// ---------------------------------------------------------------------------
// Exclusive scan of presence[262144]: per-block (1024 elems) + block sums
// ---------------------------------------------------------------------------
__device__ __forceinline__ u32 waveScanIncl(u32 x)
{
    #pragma unroll
    for (int d = 1; d < 64; d <<= 1) {
        u32 y = __shfl_up(x, d, 64);
        if ((int)(threadIdx.x & 63) >= d) x += y;
    }
    return x;
}

__global__ __launch_bounds__(256) void k_scanblocks(u32* __restrict__ data,
                                                    u32* __restrict__ bsums)
{
    int b = blockIdx.x, tid = threadIdx.x;
    int base = b * 1024 + tid * 4;
    uint4 vv = *(uint4*)(data + base);
    u32 s = vv.x + vv.y + vv.z + vv.w;
    u32 inc = waveScanIncl(s);
    __shared__ u32 wsums[4];
    int wid = tid >> 6, lane = tid & 63;
    if (lane == 63) wsums[wid] = inc;
    __syncthreads();
    u32 woff = 0;
    #pragma unroll
    for (int w = 0; w < 4; w++) if (w < wid) woff += wsums[w];
    u32 excl = woff + inc - s;
    uint4 out;
    out.x = excl; out.y = excl + vv.x; out.z = out.y + vv.y; out.w = out.z + vv.z;
    *(uint4*)(data + base) = out;
    if (tid == 255) bsums[b] = excl + s;
}

__global__ __launch_bounds__(256) void k_scansums(const u32* __restrict__ bsums,
                                                  u32* __restrict__ boff)
{
    int tid = threadIdx.x;
    u32 s = bsums[tid];
    u32 inc = waveScanIncl(s);
    __shared__ u32 wsums[4];
    int wid = tid >> 6, lane = tid & 63;
    if (lane == 63) wsums[wid] = inc;
    __syncthreads();
    u32 woff = 0;
    #pragma unroll
    for (int w = 0; w < 4; w++) if (w < wid) woff += wsums[w];
    boff[tid] = woff + inc - s;
}

// ---------------------------------------------------------------------------
// Output init: zeros for the feature region, -1.0f for the coord region
// (harness poisons d_out with 0xAA before every timed launch)
// ---------------------------------------------------------------------------
__global__ __launch_bounds__(256) void k_initout(float4* __restrict__ out,
                                                 int nfeat4, int ntot4)
{
    int stride = gridDim.x * blockDim.x;
    float4 z = {0.f, 0.f, 0.f, 0.f};
    float4 m = {-1.f, -1.f, -1.f, -1.f};
    for (int i = blockIdx.x * blockDim.x + threadIdx.x; i < ntot4; i += stride)
        out[i] = (i < nfeat4) ? z : m;
}

// ---------------------------------------------------------------------------
// Main compute: bins give wave-uniform kidx -> kernel slice is scalar (s_load).
// 512 f32 FMAs per point, then 32 atomicAdds into the ranked output row.
// ---------------------------------------------------------------------------
__global__ __launch_bounds__(256) void k_compute(
    const u32* __restrict__ binIdx, const u32* __restrict__ keyPacked,
    const float* __restrict__ feats, const float* __restrict__ kern,
    const u32* __restrict__ rank, const u32* __restrict__ boff,
    float* __restrict__ outF, float* __restrict__ outC, int npad)
{
    int slot = blockIdx.x * 256 + threadIdx.x;
    if (slot >= npad) return;
    u32 nidx = binIdx[slot];
    if (nidx == 0xFFFFFFFFu) return;   // bin padding

    u32 pk  = keyPacked[nidx];
    u32 key = pk & KEYMASK;
    // bins are 64-aligned -> kidx is wave-uniform; force to SGPR
    int kid = __builtin_amdgcn_readfirstlane((int)(pk >> 18));
    const float* __restrict__ Kp = kern + (size_t)kid * (CIN * COUT);

    const float4* fp = (const float4*)(feats + (size_t)nidx * CIN);
    float4 f0 = fp[0], f1 = fp[1], f2 = fp[2], f3 = fp[3];
    float f[CIN] = {f0.x, f0.y, f0.z, f0.w, f1.x, f1.y, f1.z, f1.w,
                    f2.x, f2.y, f2.z, f2.w, f3.x, f3.y, f3.z, f3.w};

    float acc[COUT];
    #pragma unroll
    for (int o = 0; o < COUT; o++) acc[o] = 0.f;
    #pragma unroll
    for (int i = 0; i < CIN; i++) {
        float fi = f[i];
        #pragma unroll
        for (int o = 0; o < COUT; o++)
            acc[o] = fmaf(fi, Kp[i * COUT + o], acc[o]);
    }

    u32 r = rank[key] + boff[key >> 10];
    float* dst = outF + (size_t)r * COUT;
    #pragma unroll
    for (int o = 0; o < COUT; o++) atomicAdd(dst + o, acc[o]);

    float4 cw = {(float)(key >> 12), 0.f, (float)((key >> 6) & 63u),
                 (float)(key & 63u)};
    *(float4*)(outC + (size_t)r * 4) = cw;   // benign same-value race
}

// ---------------------------------------------------------------------------
extern "C" void kernel_launch(void* const* d_in, const int* in_sizes, int n_in,
                              void* d_out, int out_size, void* d_ws, size_t ws_size,
                              hipStream_t stream)
{
    const float* feats  = (const float*)d_in[0];
    const int4*  coords = (const int4*)d_in[1];
    const float* kern   = (const float*)d_in[2];
    const int*   dstride = (const int*)d_in[3];
    int n = in_sizes[0] / CIN;

    char* ws = (char*)d_ws;
    size_t o_presence = 0;                       // KEYSPACE*4 = 1 MiB (-> rank)
    size_t o_hist     = (size_t)1 << 20;         // 64*4
    size_t o_cursor   = o_hist + 1024;           // 64*32*4 = 8 KiB (padded)
    size_t o_bsums    = o_cursor + 8192;         // 256*4
    size_t o_boff     = o_bsums + 1024;          // 256*4
    size_t o_key      = o_boff + 1024;           // n*4
    size_t o_bin      = o_key + (((size_t)n * 4 + 255) & ~(size_t)255);
    int npad = n + NKER * 64;                    // bins padded to 64-multiples

    u32* presence = (u32*)(ws + o_presence);
    u32* hist     = (u32*)(ws + o_hist);
    u32* cursor   = (u32*)(ws + o_cursor);
    u32* bsums    = (u32*)(ws + o_bsums);
    u32* boff     = (u32*)(ws + o_boff);
    u32* keyPacked= (u32*)(ws + o_key);
    u32* binIdx   = (u32*)(ws + o_bin);

    // zero presence + hist; fill binIdx with 0xFF (padding marker)
    hipMemsetAsync(ws, 0, o_hist + 1024, stream);
    hipMemsetAsync(ws + o_bin, 0xFF, (size_t)npad * 4, stream);

    int nb = (n + 255) / 256;
    k_pass1<<<nb, 256, 0, stream>>>(coords, dstride, keyPacked, presence, hist, n);
    k_binscan<<<1, 64, 0, stream>>>(hist, cursor);
    k_scatter<<<nb, 256, 0, stream>>>(keyPacked, cursor, binIdx, n);
    k_scanblocks<<<KEYSPACE / 1024, 256, 0, stream>>>(presence, bsums);
    k_scansums<<<1, 256, 0, stream>>>(bsums, boff);
    k_initout<<<2048, 256, 0, stream>>>((float4*)d_out, n * COUT / 4,
                                        n * (COUT + 4) / 4);
    int nbp = (npad + 255) / 256;
    k_compute<<<nbp, 256, 0, stream>>>(binIdx, keyPacked, feats, kern,
                                       presence /*rank*/, boff,
                                       (float*)d_out,
                                       (float*)d_out + (size_t)n * COUT, npad);
}

// Round 4
// 474.059 us; speedup vs baseline: 4.2852x; 4.2852x over previous
//
#include <hip/hip_runtime.h>
#include <stdint.h>

typedef unsigned int u32;
typedef unsigned long long u64;

#define CIN   16
#define COUT  32
#define NKER  64
#define KEYSPACE 262144   // 64^3
#define KEYMASK  0x3FFFFu

// bf16 round-to-nearest-even pack/unpack (values are finite)
__device__ __forceinline__ u32 f2bf(float f) {
    u32 x = __builtin_bit_cast(u32, f);
    return (x + 0x7FFFu + ((x >> 16) & 1u)) >> 16;
}
__device__ __forceinline__ float bf2f(u32 h) {
    return __builtin_bit_cast(float, h << 16);
}

// ---------------------------------------------------------------------------
// Pass 1: keyPacked, per-key point count (1 atomic/point), kidx histogram
// ---------------------------------------------------------------------------
__global__ __launch_bounds__(256) void k_pass1(
    const int4* __restrict__ coords, const int* __restrict__ dstride,
    u32* __restrict__ keyPacked, u32* __restrict__ countKey,
    u32* __restrict__ hist, int n)
{
    __shared__ u32 lh[NKER];
    int tid = threadIdx.x;
    if (tid < NKER) lh[tid] = 0;
    __syncthreads();
    int i = blockIdx.x * 256 + tid;
    if (i < n) {
        int4 c = coords[i];
        int s = dstride[0];
        u32 kid = (u32)(c.y / s);
        u32 key = ((u32)c.x << 12) | ((u32)c.z << 6) | (u32)c.w;
        keyPacked[i] = key | (kid << 18);
        atomicAdd(&countKey[key], 1u);
        atomicAdd(&lh[kid], 1u);
    }
    __syncthreads();
    if (tid < NKER && lh[tid]) atomicAdd(&hist[tid], lh[tid]);
}

// ---------------------------------------------------------------------------
// Wave-scan of 64 bin counts (padded to 64-multiples) -> bin cursors
// ---------------------------------------------------------------------------
__global__ void k_binscan(const u32* __restrict__ hist, u32* __restrict__ cursor)
{
    int k = threadIdx.x;                 // 64 threads, one wave
    u32 x = (hist[k] + 63u) & ~63u;
    u32 inc = x;
    #pragma unroll
    for (int d = 1; d < 64; d <<= 1) {
        u32 y = __shfl_up(inc, d, 64);
        if (k >= d) inc += y;
    }
    cursor[k * 32] = inc - x;            // exclusive, cursors 128B apart
}

// ---------------------------------------------------------------------------
// Scatter (point idx, packed key) into kidx bins (block-aggregated cursors)
// ---------------------------------------------------------------------------
__global__ __launch_bounds__(256) void k_scatter(
    const u32* __restrict__ keyPacked, u32* __restrict__ cursor,
    uint2* __restrict__ binPts, int n)
{
    __shared__ u32 lh[NKER];
    __shared__ u32 lbase[NKER];
    int tid = threadIdx.x;
    if (tid < NKER) lh[tid] = 0;
    __syncthreads();
    int i = blockIdx.x * 256 + tid;
    u32 pk = 0, kid = 0, pos = 0;
    bool v = i < n;
    if (v) {
        pk = keyPacked[i];
        kid = pk >> 18;
        pos = atomicAdd(&lh[kid], 1u);
    }
    __syncthreads();
    if (tid < NKER && lh[tid]) lbase[tid] = atomicAdd(&cursor[tid * 32], lh[tid]);
    __syncthreads();
    if (v) binPts[lbase[kid] + pos] = make_uint2((u32)i, pk);
}

// ---------------------------------------------------------------------------
// Packed u64 scan over countKey: lo32 = point-start scan, hi32 = rank scan
// ---------------------------------------------------------------------------
__device__ __forceinline__ u64 waveScanIncl64(u64 x)
{
    #pragma unroll
    for (int d = 1; d < 64; d <<= 1) {
        u64 y = __shfl_up(x, d, 64);
        if ((int)(threadIdx.x & 63) >= d) x += y;
    }
    return x;
}

__global__ __launch_bounds__(256) void k_scanblocks(
    const u32* __restrict__ countKey, u64* __restrict__ psRank,
    u64* __restrict__ bsums)
{
    int b = blockIdx.x, tid = threadIdx.x;
    int base = b * 1024 + tid * 4;
    uint4 c = *(const uint4*)(countKey + base);
    u64 e0 = (u64)c.x | ((u64)(c.x ? 1u : 0u) << 32);
    u64 e1 = (u64)c.y | ((u64)(c.y ? 1u : 0u) << 32);
    u64 e2 = (u64)c.z | ((u64)(c.z ? 1u : 0u) << 32);
    u64 e3 = (u64)c.w | ((u64)(c.w ? 1u : 0u) << 32);
    u64 s = e0 + e1 + e2 + e3;
    u64 inc = waveScanIncl64(s);
    __shared__ u64 wsums[4];
    int wid = tid >> 6, lane = tid & 63;
    if (lane == 63) wsums[wid] = inc;
    __syncthreads();
    u64 woff = 0;
    #pragma unroll
    for (int w = 0; w < 4; w++) if (w < wid) woff += wsums[w];
    u64 excl = woff + inc - s;
    u64* dst = psRank + base;
    dst[0] = excl; dst[1] = excl + e0; dst[2] = excl + e0 + e1;
    dst[3] = excl + e0 + e1 + e2;
    if (tid == 255) bsums[b] = excl + s;
}

__global__ __launch_bounds__(256) void k_scansums(
    const u64* __restrict__ bsums, u64* __restrict__ boff, u32* __restrict__ totals)
{
    int tid = threadIdx.x;
    u64 s = bsums[tid];
    u64 inc = waveScanIncl64(s);
    __shared__ u64 wsums[4];
    int wid = tid >> 6, lane = tid & 63;
    if (lane == 63) wsums[wid] = inc;
    __syncthreads();
    u64 woff = 0;
    #pragma unroll
    for (int w = 0; w < 4; w++) if (w < wid) woff += wsums[w];
    boff[tid] = woff + inc - s;
    if (tid == 255) totals[0] = (u32)((woff + inc) >> 32);   // U = #unique keys
}

// ---------------------------------------------------------------------------
// Per present key: unique-key list, segment starts, point cursor init
// ---------------------------------------------------------------------------
__global__ __launch_bounds__(256) void k_fillseg(
    const u32* __restrict__ countKey, const u64* __restrict__ psRank,
    const u64* __restrict__ boff, const u32* __restrict__ totals,
    u32* __restrict__ uniqKey, u32* __restrict__ segStart,
    u32* __restrict__ pointCur, int n)
{
    int key = blockIdx.x * 256 + threadIdx.x;
    u32 cnt = countKey[key];
    if (cnt) {
        u64 e = psRank[key] + boff[key >> 10];
        u32 r = (u32)(e >> 32), s = (u32)e;
        uniqKey[r] = key;
        segStart[r] = s;
        pointCur[key] = s;
    }
    if (key == 0) segStart[totals[0]] = (u32)n;
}

// ---------------------------------------------------------------------------
// Main compute (primary): wave-uniform kid -> SGPR kernel; one u32 atomic for
// the scratch slot; 64B bf16 row plain-stored into key-sorted scratch.
// ---------------------------------------------------------------------------
__global__ __launch_bounds__(256) void k_compute(
    const uint2* __restrict__ binPts, const float* __restrict__ feats,
    const float* __restrict__ kern, u32* __restrict__ pointCur,
    uint4* __restrict__ scratch, int npad)
{
    int slot = blockIdx.x * 256 + threadIdx.x;
    if (slot >= npad) return;
    uint2 p = binPts[slot];
    if (p.x == 0xFFFFFFFFu) return;        // bin padding
    u32 nidx = p.x, pk = p.y, key = pk & KEYMASK;
    int kid = __builtin_amdgcn_readfirstlane((int)(pk >> 18));
    const float* __restrict__ Kp = kern + (size_t)kid * (CIN * COUT);

    const float4* fp = (const float4*)(feats + (size_t)nidx * CIN);
    float4 f0 = fp[0], f1 = fp[1], f2 = fp[2], f3 = fp[3];
    float f[CIN] = {f0.x, f0.y, f0.z, f0.w, f1.x, f1.y, f1.z, f1.w,
                    f2.x, f2.y, f2.z, f2.w, f3.x, f3.y, f3.z, f3.w};

    float acc[COUT];
    #pragma unroll
    for (int o = 0; o < COUT; o++) acc[o] = 0.f;
    #pragma unroll
    for (int i = 0; i < CIN; i++) {
        float fi = f[i];
        #pragma unroll
        for (int o = 0; o < COUT; o++)
            acc[o] = fmaf(fi, Kp[i * COUT + o], acc[o]);
    }

    u32 pos = atomicAdd(&pointCur[key], 1u);
    uint4* dst = scratch + (size_t)pos * 4;
    #pragma unroll
    for (int q = 0; q < 4; q++) {
        uint4 o;
        o.x = f2bf(acc[q * 8 + 0]) | (f2bf(acc[q * 8 + 1]) << 16);
        o.y = f2bf(acc[q * 8 + 2]) | (f2bf(acc[q * 8 + 3]) << 16);
        o.z = f2bf(acc[q * 8 + 4]) | (f2bf(acc[q * 8 + 5]) << 16);
        o.w = f2bf(acc[q * 8 + 6]) | (f2bf(acc[q * 8 + 7]) << 16);
        dst[q] = o;
    }
}

// ---------------------------------------------------------------------------
// Gather-reduce: 4 threads per output row, contiguous segment reads,
// every output row (feats + coords) written exactly once. No init pass.
// ---------------------------------------------------------------------------
__global__ __launch_bounds__(256) void k_reduce(
    const uint4* __restrict__ scratch, const u32* __restrict__ segStart,
    const u32* __restrict__ uniqKey, const u32* __restrict__ totals,
    float* __restrict__ outF, float* __restrict__ outC, int n)
{
    int gid = blockIdx.x * 256 + threadIdx.x;
    int r = gid >> 2, t = gid & 3;
    if (r >= n) return;
    u32 U = totals[0];
    float4* dst = (float4*)(outF + (size_t)r * COUT + t * 8);
    if (r < (int)U) {
        u32 s0 = segStart[r], s1 = segStart[r + 1];
        float a0 = 0.f, a1 = 0.f, a2 = 0.f, a3 = 0.f;
        float a4 = 0.f, a5 = 0.f, a6 = 0.f, a7 = 0.f;
        for (u32 j = s0; j < s1; j++) {
            uint4 v = scratch[(size_t)j * 4 + t];
            a0 += bf2f(v.x & 0xFFFFu); a1 += bf2f(v.x >> 16);
            a2 += bf2f(v.y & 0xFFFFu); a3 += bf2f(v.y >> 16);
            a4 += bf2f(v.z & 0xFFFFu); a5 += bf2f(v.z >> 16);
            a6 += bf2f(v.w & 0xFFFFu); a7 += bf2f(v.w >> 16);
        }
        dst[0] = make_float4(a0, a1, a2, a3);
        dst[1] = make_float4(a4, a5, a6, a7);
        if (t == 0) {
            u32 k = uniqKey[r];
            *(float4*)(outC + (size_t)r * 4) =
                make_float4((float)(k >> 12), 0.f, (float)((k >> 6) & 63u),
                            (float)(k & 63u));
        }
    } else {
        float4 z = make_float4(0.f, 0.f, 0.f, 0.f);
        dst[0] = z; dst[1] = z;
        if (t == 0)
            *(float4*)(outC + (size_t)r * 4) =
                make_float4(-1.f, -1.f, -1.f, -1.f);
    }
}

// ---------------------------------------------------------------------------
// Fallback path (small ws): round-2 proven atomic accumulation
// ---------------------------------------------------------------------------
__global__ __launch_bounds__(256) void k_initout(float4* __restrict__ out,
                                                 int nfeat4, int ntot4)
{
    int stride = gridDim.x * blockDim.x;
    float4 z = {0.f, 0.f, 0.f, 0.f};
    float4 m = {-1.f, -1.f, -1.f, -1.f};
    for (int i = blockIdx.x * blockDim.x + threadIdx.x; i < ntot4; i += stride)
        out[i] = (i < nfeat4) ? z : m;
}

__global__ __launch_bounds__(256) void k_computeA(
    const uint2* __restrict__ binPts, const float* __restrict__ feats,
    const float* __restrict__ kern, const u64* __restrict__ psRank,
    const u64* __restrict__ boff, float* __restrict__ outF,
    float* __restrict__ outC, int npad)
{
    int slot = blockIdx.x * 256 + threadIdx.x;
    if (slot >= npad) return;
    uint2 p = binPts[slot];
    if (p.x == 0xFFFFFFFFu) return;
    u32 nidx = p.x, pk = p.y, key = pk & KEYMASK;
    int kid = __builtin_amdgcn_readfirstlane((int)(pk >> 18));
    const float* __restrict__ Kp = kern + (size_t)kid * (CIN * COUT);

    const float4* fp = (const float4*)(feats + (size_t)nidx * CIN);
    float4 f0 = fp[0], f1 = fp[1], f2 = fp[2], f3 = fp[3];
    float f[CIN] = {f0.x, f0.y, f0.z, f0.w, f1.x, f1.y, f1.z, f1.w,
                    f2.x, f2.y, f2.z, f2.w, f3.x, f3.y, f3.z, f3.w};

    float acc[COUT];
    #pragma unroll
    for (int o = 0; o < COUT; o++) acc[o] = 0.f;
    #pragma unroll
    for (int i = 0; i < CIN; i++) {
        float fi = f[i];
        #pragma unroll
        for (int o = 0; o < COUT; o++)
            acc[o] = fmaf(fi, Kp[i * COUT + o], acc[o]);
    }

    u64 e = psRank[key] + boff[key >> 10];
    u32 r = (u32)(e >> 32);
    float* dst = outF + (size_t)r * COUT;
    #pragma unroll
    for (int o = 0; o < COUT; o++) atomicAdd(dst + o, acc[o]);
    float4 cw = {(float)(key >> 12), 0.f, (float)((key >> 6) & 63u),
                 (float)(key & 63u)};
    *(float4*)(outC + (size_t)r * 4) = cw;
}

// ---------------------------------------------------------------------------
extern "C" void kernel_launch(void* const* d_in, const int* in_sizes, int n_in,
                              void* d_out, int out_size, void* d_ws, size_t ws_size,
                              hipStream_t stream)
{
    const float* feats   = (const float*)d_in[0];
    const int4*  coords  = (const int4*)d_in[1];
    const float* kern    = (const float*)d_in[2];
    const int*   dstride = (const int*)d_in[3];
    int n = in_sizes[0] / CIN;
    int npad = n + NKER * 64;

    char* ws = (char*)d_ws;
    size_t o_countKey = 0;                                   // 1 MiB
    size_t o_psRank   = o_countKey + (size_t)KEYSPACE * 4;   // 2 MiB
    size_t o_hist     = o_psRank + (size_t)KEYSPACE * 8;     // 256B (pad 1K)
    size_t o_cursor   = o_hist + 1024;                       // 8 KiB
    size_t o_bsums    = o_cursor + 8192;                     // 2 KiB
    size_t o_boff     = o_bsums + 2048;                      // 2 KiB
    size_t o_totals   = o_boff + 2048;                       // 256 B
    size_t o_uniq     = o_totals + 256;                      // 1 MiB
    size_t o_pcur     = o_uniq + (size_t)KEYSPACE * 4;       // 1 MiB
    size_t o_seg      = o_pcur + (size_t)KEYSPACE * 4;       // (n+2)*4
    size_t o_key      = o_seg + (((size_t)(n + 2) * 4 + 255) & ~(size_t)255);
    size_t o_bin      = o_key + (((size_t)n * 4 + 255) & ~(size_t)255);
    size_t o_scratch  = (o_bin + (size_t)npad * 8 + 255) & ~(size_t)255;
    size_t need       = o_scratch + (size_t)n * 64;          // bf16 scratch
    bool big = ws_size >= need;

    u32*   countKey = (u32*)(ws + o_countKey);
    u64*   psRank   = (u64*)(ws + o_psRank);
    u32*   hist     = (u32*)(ws + o_hist);
    u32*   cursor   = (u32*)(ws + o_cursor);
    u64*   bsums    = (u64*)(ws + o_bsums);
    u64*   boff     = (u64*)(ws + o_boff);
    u32*   totals   = (u32*)(ws + o_totals);
    u32*   uniqKey  = (u32*)(ws + o_uniq);
    u32*   pointCur = (u32*)(ws + o_pcur);
    u32*   segStart = (u32*)(ws + o_seg);
    u32*   keyPacked= (u32*)(ws + o_key);
    uint2* binPts   = (uint2*)(ws + o_bin);
    uint4* scratch  = (uint4*)(ws + o_scratch);

    hipMemsetAsync(ws + o_countKey, 0, (size_t)KEYSPACE * 4, stream);
    hipMemsetAsync(ws + o_hist, 0, 1024, stream);
    hipMemsetAsync(ws + o_bin, 0xFF, (size_t)npad * 8, stream);

    int nb = (n + 255) / 256;
    k_pass1<<<nb, 256, 0, stream>>>(coords, dstride, keyPacked, countKey, hist, n);
    k_binscan<<<1, 64, 0, stream>>>(hist, cursor);
    k_scatter<<<nb, 256, 0, stream>>>(keyPacked, cursor, binPts, n);
    k_scanblocks<<<KEYSPACE / 1024, 256, 0, stream>>>(countKey, psRank, bsums);
    k_scansums<<<1, 256, 0, stream>>>(bsums, boff, totals);
    k_fillseg<<<KEYSPACE / 256, 256, 0, stream>>>(countKey, psRank, boff, totals,
                                                  uniqKey, segStart, pointCur, n);
    int nbp = (npad + 255) / 256;
    if (big) {
        k_compute<<<nbp, 256, 0, stream>>>(binPts, feats, kern, pointCur,
                                           scratch, npad);
        int nthr = n * 4;
        k_reduce<<<(nthr + 255) / 256, 256, 0, stream>>>(scratch, segStart,
                                                         uniqKey, totals,
                                                         (float*)d_out,
                                                         (float*)d_out + (size_t)n * COUT,
                                                         n);
    } else {
        k_initout<<<2048, 256, 0, stream>>>((float4*)d_out, n * COUT / 4,
                                            n * (COUT + 4) / 4);
        k_computeA<<<nbp, 256, 0, stream>>>(binPts, feats, kern, psRank, boff,
                                            (float*)d_out,
                                            (float*)d_out + (size_t)n * COUT,
                                            npad);
    }
}

// Round 5
// 355.093 us; speedup vs baseline: 5.7209x; 1.3350x over previous
//
#include <hip/hip_runtime.h>
#include <stdint.h>

typedef unsigned int u32;
typedef unsigned long long u64;

#define CIN   16
#define COUT  32
#define NKER  64
#define KEYSPACE 262144   // 64^3
#define KEYMASK  0x3FFFFu
#define PTS_PER_BLK 1024
#define HIST_ROWS 16

// bf16 round-to-nearest-even pack/unpack (values are finite)
__device__ __forceinline__ u32 f2bf(float f) {
    u32 x = __builtin_bit_cast(u32, f);
    return (x + 0x7FFFu + ((x >> 16) & 1u)) >> 16;
}
__device__ __forceinline__ float bf2f(u32 h) {
    return __builtin_bit_cast(float, h << 16);
}

// ---------------------------------------------------------------------------
// Pass 1 (grid-stride 1024 pts/block): keyPacked gets key|kid|pos where pos is
// the atomicAdd return (within-key slot). Privatized 16-row hist cuts flush
// line-contention 64x vs round-4.
// ---------------------------------------------------------------------------
__global__ __launch_bounds__(256) void k_pass1(
    const int4* __restrict__ coords, const int* __restrict__ dstride,
    u32* __restrict__ keyPacked, u32* __restrict__ countKey,
    u32* __restrict__ histp, int n)
{
    __shared__ u32 lh[NKER];
    int tid = threadIdx.x;
    if (tid < NKER) lh[tid] = 0;
    __syncthreads();
    int s = dstride[0];
    int base = blockIdx.x * PTS_PER_BLK;
    #pragma unroll
    for (int t = 0; t < PTS_PER_BLK / 256; t++) {
        int i = base + t * 256 + tid;
        if (i < n) {
            int4 c = coords[i];
            u32 kid = (u32)(c.y / s);
            u32 key = ((u32)c.x << 12) | ((u32)c.z << 6) | (u32)c.w;
            u32 pos = atomicAdd(&countKey[key], 1u);
            keyPacked[i] = key | (kid << 18) | (pos << 24);
            atomicAdd(&lh[kid], 1u);
        }
    }
    __syncthreads();
    if (tid < NKER && lh[tid])
        atomicAdd(&histp[(blockIdx.x & (HIST_ROWS - 1)) * NKER + tid], lh[tid]);
}

// ---------------------------------------------------------------------------
// Wave-scan of 64 bin counts (summing 16 hist rows, padded to 64-multiples)
// ---------------------------------------------------------------------------
__global__ void k_binscan(const u32* __restrict__ histp, u32* __restrict__ cursor)
{
    int k = threadIdx.x;                 // 64 threads, one wave
    u32 h = 0;
    #pragma unroll
    for (int r = 0; r < HIST_ROWS; r++) h += histp[r * NKER + k];
    u32 x = (h + 63u) & ~63u;
    u32 inc = x;
    #pragma unroll
    for (int d = 1; d < 64; d <<= 1) {
        u32 y = __shfl_up(inc, d, 64);
        if (k >= d) inc += y;
    }
    cursor[k * 32] = inc - x;            // exclusive, cursors 128B apart
}

// ---------------------------------------------------------------------------
// Scatter (grid-stride, two-phase): one cursor flush per 1024 points
// ---------------------------------------------------------------------------
__global__ __launch_bounds__(256) void k_scatter(
    const u32* __restrict__ keyPacked, u32* __restrict__ cursor,
    uint2* __restrict__ binPts, int n)
{
    __shared__ u32 lh[NKER];
    __shared__ u32 lbase[NKER];
    __shared__ u32 cnt2[NKER];
    int tid = threadIdx.x;
    if (tid < NKER) { lh[tid] = 0; cnt2[tid] = 0; }
    __syncthreads();
    int base = blockIdx.x * PTS_PER_BLK;
    u32 pk0 = 0, pk1 = 0, pk2 = 0, pk3 = 0;
    u32 vmask = 0;
    {
        int i0 = base + 0 * 256 + tid;
        int i1 = base + 1 * 256 + tid;
        int i2 = base + 2 * 256 + tid;
        int i3 = base + 3 * 256 + tid;
        if (i0 < n) { pk0 = keyPacked[i0]; vmask |= 1u; atomicAdd(&lh[(pk0 >> 18) & 63u], 1u); }
        if (i1 < n) { pk1 = keyPacked[i1]; vmask |= 2u; atomicAdd(&lh[(pk1 >> 18) & 63u], 1u); }
        if (i2 < n) { pk2 = keyPacked[i2]; vmask |= 4u; atomicAdd(&lh[(pk2 >> 18) & 63u], 1u); }
        if (i3 < n) { pk3 = keyPacked[i3]; vmask |= 8u; atomicAdd(&lh[(pk3 >> 18) & 63u], 1u); }
    }
    __syncthreads();
    if (tid < NKER && lh[tid]) lbase[tid] = atomicAdd(&cursor[tid * 32], lh[tid]);
    __syncthreads();
    if (vmask & 1u) { u32 kd = (pk0 >> 18) & 63u; u32 p = atomicAdd(&cnt2[kd], 1u);
                      binPts[lbase[kd] + p] = make_uint2((u32)(base + 0 * 256 + tid), pk0); }
    if (vmask & 2u) { u32 kd = (pk1 >> 18) & 63u; u32 p = atomicAdd(&cnt2[kd], 1u);
                      binPts[lbase[kd] + p] = make_uint2((u32)(base + 1 * 256 + tid), pk1); }
    if (vmask & 4u) { u32 kd = (pk2 >> 18) & 63u; u32 p = atomicAdd(&cnt2[kd], 1u);
                      binPts[lbase[kd] + p] = make_uint2((u32)(base + 2 * 256 + tid), pk2); }
    if (vmask & 8u) { u32 kd = (pk3 >> 18) & 63u; u32 p = atomicAdd(&cnt2[kd], 1u);
                      binPts[lbase[kd] + p] = make_uint2((u32)(base + 3 * 256 + tid), pk3); }
}

// ---------------------------------------------------------------------------
// Packed u64 scan over countKey: lo32 = point-start scan, hi32 = rank scan
// ---------------------------------------------------------------------------
__device__ __forceinline__ u64 waveScanIncl64(u64 x)
{
    #pragma unroll
    for (int d = 1; d < 64; d <<= 1) {
        u64 y = __shfl_up(x, d, 64);
        if ((int)(threadIdx.x & 63) >= d) x += y;
    }
    return x;
}

__global__ __launch_bounds__(256) void k_scanblocks(
    const u32* __restrict__ countKey, u64* __restrict__ psRank,
    u64* __restrict__ bsums)
{
    int b = blockIdx.x, tid = threadIdx.x;
    int base = b * 1024 + tid * 4;
    uint4 c = *(const uint4*)(countKey + base);
    u64 e0 = (u64)c.x | ((u64)(c.x ? 1u : 0u) << 32);
    u64 e1 = (u64)c.y | ((u64)(c.y ? 1u : 0u) << 32);
    u64 e2 = (u64)c.z | ((u64)(c.z ? 1u : 0u) << 32);
    u64 e3 = (u64)c.w | ((u64)(c.w ? 1u : 0u) << 32);
    u64 s = e0 + e1 + e2 + e3;
    u64 inc = waveScanIncl64(s);
    __shared__ u64 wsums[4];
    int wid = tid >> 6, lane = tid & 63;
    if (lane == 63) wsums[wid] = inc;
    __syncthreads();
    u64 woff = 0;
    #pragma unroll
    for (int w = 0; w < 4; w++) if (w < wid) woff += wsums[w];
    u64 excl = woff + inc - s;
    u64* dst = psRank + base;
    dst[0] = excl; dst[1] = excl + e0; dst[2] = excl + e0 + e1;
    dst[3] = excl + e0 + e1 + e2;
    if (tid == 255) bsums[b] = excl + s;
}

__global__ __launch_bounds__(256) void k_scansums(
    const u64* __restrict__ bsums, u64* __restrict__ boff, u32* __restrict__ totals)
{
    int tid = threadIdx.x;
    u64 s = bsums[tid];
    u64 inc = waveScanIncl64(s);
    __shared__ u64 wsums[4];
    int wid = tid >> 6, lane = tid & 63;
    if (lane == 63) wsums[wid] = inc;
    __syncthreads();
    u64 woff = 0;
    #pragma unroll
    for (int w = 0; w < 4; w++) if (w < wid) woff += wsums[w];
    boff[tid] = woff + inc - s;
    if (tid == 255) totals[0] = (u32)((woff + inc) >> 32);   // U = #unique keys
}

// ---------------------------------------------------------------------------
// Per present key: unique-key list, segment starts, point-start table
// (pointStart is READ-ONLY downstream — no atomics in compute)
// ---------------------------------------------------------------------------
__global__ __launch_bounds__(256) void k_fillseg(
    const u32* __restrict__ countKey, const u64* __restrict__ psRank,
    const u64* __restrict__ boff, const u32* __restrict__ totals,
    u32* __restrict__ uniqKey, u32* __restrict__ segStart,
    u32* __restrict__ pointStart, int n)
{
    int key = blockIdx.x * 256 + threadIdx.x;
    u32 cnt = countKey[key];
    if (cnt) {
        u64 e = psRank[key] + boff[key >> 10];
        u32 r = (u32)(e >> 32), s = (u32)e;
        uniqKey[r] = key;
        segStart[r] = s;
        pointStart[key] = s;
    }
    if (key == 0) segStart[totals[0]] = (u32)n;
}

// ---------------------------------------------------------------------------
// Main compute: wave-uniform kid -> SGPR kernel; ZERO atomics — the scratch
// slot is pointStart[key] + pos (pos carried in keyPacked bits 31:24).
// ---------------------------------------------------------------------------
__global__ __launch_bounds__(256) void k_compute(
    const uint2* __restrict__ binPts, const float* __restrict__ feats,
    const float* __restrict__ kern, const u32* __restrict__ pointStart,
    uint4* __restrict__ scratch, int npad)
{
    int slot = blockIdx.x * 256 + threadIdx.x;
    if (slot >= npad) return;
    uint2 p = binPts[slot];
    if (p.x == 0xFFFFFFFFu) return;        // bin padding
    u32 nidx = p.x, pk = p.y, key = pk & KEYMASK;
    u32 pos = pk >> 24;
    u32 ps = pointStart[key];              // issue early, hide under FMAs
    int kid = __builtin_amdgcn_readfirstlane((int)((pk >> 18) & 63u));
    const float* __restrict__ Kp = kern + (size_t)kid * (CIN * COUT);

    const float4* fp = (const float4*)(feats + (size_t)nidx * CIN);
    float4 f0 = fp[0], f1 = fp[1], f2 = fp[2], f3 = fp[3];
    float f[CIN] = {f0.x, f0.y, f0.z, f0.w, f1.x, f1.y, f1.z, f1.w,
                    f2.x, f2.y, f2.z, f2.w, f3.x, f3.y, f3.z, f3.w};

    float acc[COUT];
    #pragma unroll
    for (int o = 0; o < COUT; o++) acc[o] = 0.f;
    #pragma unroll
    for (int i = 0; i < CIN; i++) {
        float fi = f[i];
        #pragma unroll
        for (int o = 0; o < COUT; o++)
            acc[o] = fmaf(fi, Kp[i * COUT + o], acc[o]);
    }

    uint4* dst = scratch + (size_t)(ps + pos) * 4;
    #pragma unroll
    for (int q = 0; q < 4; q++) {
        uint4 o;
        o.x = f2bf(acc[q * 8 + 0]) | (f2bf(acc[q * 8 + 1]) << 16);
        o.y = f2bf(acc[q * 8 + 2]) | (f2bf(acc[q * 8 + 3]) << 16);
        o.z = f2bf(acc[q * 8 + 4]) | (f2bf(acc[q * 8 + 5]) << 16);
        o.w = f2bf(acc[q * 8 + 6]) | (f2bf(acc[q * 8 + 7]) << 16);
        dst[q] = o;
    }
}

// ---------------------------------------------------------------------------
// Gather-reduce: 4 threads per output row, contiguous segment reads,
// every output row (feats + coords) written exactly once. No init pass.
// ---------------------------------------------------------------------------
__global__ __launch_bounds__(256) void k_reduce(
    const uint4* __restrict__ scratch, const u32* __restrict__ segStart,
    const u32* __restrict__ uniqKey, const u32* __restrict__ totals,
    float* __restrict__ outF, float* __restrict__ outC, int n)
{
    int gid = blockIdx.x * 256 + threadIdx.x;
    int r = gid >> 2, t = gid & 3;
    if (r >= n) return;
    u32 U = totals[0];
    float4* dst = (float4*)(outF + (size_t)r * COUT + t * 8);
    if (r < (int)U) {
        u32 s0 = segStart[r], s1 = segStart[r + 1];
        float a0 = 0.f, a1 = 0.f, a2 = 0.f, a3 = 0.f;
        float a4 = 0.f, a5 = 0.f, a6 = 0.f, a7 = 0.f;
        for (u32 j = s0; j < s1; j++) {
            uint4 v = scratch[(size_t)j * 4 + t];
            a0 += bf2f(v.x & 0xFFFFu); a1 += bf2f(v.x >> 16);
            a2 += bf2f(v.y & 0xFFFFu); a3 += bf2f(v.y >> 16);
            a4 += bf2f(v.z & 0xFFFFu); a5 += bf2f(v.z >> 16);
            a6 += bf2f(v.w & 0xFFFFu); a7 += bf2f(v.w >> 16);
        }
        dst[0] = make_float4(a0, a1, a2, a3);
        dst[1] = make_float4(a4, a5, a6, a7);
        if (t == 0) {
            u32 k = uniqKey[r];
            *(float4*)(outC + (size_t)r * 4) =
                make_float4((float)(k >> 12), 0.f, (float)((k >> 6) & 63u),
                            (float)(k & 63u));
        }
    } else {
        float4 z = make_float4(0.f, 0.f, 0.f, 0.f);
        dst[0] = z; dst[1] = z;
        if (t == 0)
            *(float4*)(outC + (size_t)r * 4) =
                make_float4(-1.f, -1.f, -1.f, -1.f);
    }
}

// ---------------------------------------------------------------------------
// Fallback path (small ws): round-2 proven atomic accumulation
// ---------------------------------------------------------------------------
__global__ __launch_bounds__(256) void k_initout(float4* __restrict__ out,
                                                 int nfeat4, int ntot4)
{
    int stride = gridDim.x * blockDim.x;
    float4 z = {0.f, 0.f, 0.f, 0.f};
    float4 m = {-1.f, -1.f, -1.f, -1.f};
    for (int i = blockIdx.x * blockDim.x + threadIdx.x; i < ntot4; i += stride)
        out[i] = (i < nfeat4) ? z : m;
}

__global__ __launch_bounds__(256) void k_computeA(
    const uint2* __restrict__ binPts, const float* __restrict__ feats,
    const float* __restrict__ kern, const u64* __restrict__ psRank,
    const u64* __restrict__ boff, float* __restrict__ outF,
    float* __restrict__ outC, int npad)
{
    int slot = blockIdx.x * 256 + threadIdx.x;
    if (slot >= npad) return;
    uint2 p = binPts[slot];
    if (p.x == 0xFFFFFFFFu) return;
    u32 nidx = p.x, pk = p.y, key = pk & KEYMASK;
    int kid = __builtin_amdgcn_readfirstlane((int)((pk >> 18) & 63u));
    const float* __restrict__ Kp = kern + (size_t)kid * (CIN * COUT);

    const float4* fp = (const float4*)(feats + (size_t)nidx * CIN);
    float4 f0 = fp[0], f1 = fp[1], f2 = fp[2], f3 = fp[3];
    float f[CIN] = {f0.x, f0.y, f0.z, f0.w, f1.x, f1.y, f1.z, f1.w,
                    f2.x, f2.y, f2.z, f2.w, f3.x, f3.y, f3.z, f3.w};

    float acc[COUT];
    #pragma unroll
    for (int o = 0; o < COUT; o++) acc[o] = 0.f;
    #pragma unroll
    for (int i = 0; i < CIN; i++) {
        float fi = f[i];
        #pragma unroll
        for (int o = 0; o < COUT; o++)
            acc[o] = fmaf(fi, Kp[i * COUT + o], acc[o]);
    }

    u64 e = psRank[key] + boff[key >> 10];
    u32 r = (u32)(e >> 32);
    float* dst = outF + (size_t)r * COUT;
    #pragma unroll
    for (int o = 0; o < COUT; o++) atomicAdd(dst + o, acc[o]);
    float4 cw = {(float)(key >> 12), 0.f, (float)((key >> 6) & 63u),
                 (float)(key & 63u)};
    *(float4*)(outC + (size_t)r * 4) = cw;
}

// ---------------------------------------------------------------------------
extern "C" void kernel_launch(void* const* d_in, const int* in_sizes, int n_in,
                              void* d_out, int out_size, void* d_ws, size_t ws_size,
                              hipStream_t stream)
{
    const float* feats   = (const float*)d_in[0];
    const int4*  coords  = (const int4*)d_in[1];
    const float* kern    = (const float*)d_in[2];
    const int*   dstride = (const int*)d_in[3];
    int n = in_sizes[0] / CIN;
    int npad = n + NKER * 64;

    char* ws = (char*)d_ws;
    size_t o_countKey = 0;                                   // 1 MiB
    size_t o_psRank   = o_countKey + (size_t)KEYSPACE * 4;   // 2 MiB
    size_t o_hist     = o_psRank + (size_t)KEYSPACE * 8;     // 4 KiB
    size_t o_cursor   = o_hist + (size_t)HIST_ROWS * NKER * 4; // 8 KiB
    size_t o_bsums    = o_cursor + 8192;                     // 2 KiB
    size_t o_boff     = o_bsums + 2048;                      // 2 KiB
    size_t o_totals   = o_boff + 2048;                       // 256 B
    size_t o_uniq     = o_totals + 256;                      // 1 MiB
    size_t o_pstart   = o_uniq + (size_t)KEYSPACE * 4;       // 1 MiB
    size_t o_seg      = o_pstart + (size_t)KEYSPACE * 4;     // (n+2)*4
    size_t o_key      = o_seg + (((size_t)(n + 2) * 4 + 255) & ~(size_t)255);
    size_t o_bin      = o_key + (((size_t)n * 4 + 255) & ~(size_t)255);
    size_t o_scratch  = (o_bin + (size_t)npad * 8 + 255) & ~(size_t)255;
    size_t need       = o_scratch + (size_t)n * 64;          // bf16 scratch
    bool big = ws_size >= need;

    u32*   countKey  = (u32*)(ws + o_countKey);
    u64*   psRank    = (u64*)(ws + o_psRank);
    u32*   histp     = (u32*)(ws + o_hist);
    u32*   cursor    = (u32*)(ws + o_cursor);
    u64*   bsums     = (u64*)(ws + o_bsums);
    u64*   boff      = (u64*)(ws + o_boff);
    u32*   totals    = (u32*)(ws + o_totals);
    u32*   uniqKey   = (u32*)(ws + o_uniq);
    u32*   pointStart= (u32*)(ws + o_pstart);
    u32*   segStart  = (u32*)(ws + o_seg);
    u32*   keyPacked = (u32*)(ws + o_key);
    uint2* binPts    = (uint2*)(ws + o_bin);
    uint4* scratch   = (uint4*)(ws + o_scratch);

    hipMemsetAsync(ws + o_countKey, 0, (size_t)KEYSPACE * 4, stream);
    hipMemsetAsync(ws + o_hist, 0, (size_t)HIST_ROWS * NKER * 4, stream);
    hipMemsetAsync(ws + o_bin, 0xFF, (size_t)npad * 8, stream);

    int nblk = (n + PTS_PER_BLK - 1) / PTS_PER_BLK;
    k_pass1<<<nblk, 256, 0, stream>>>(coords, dstride, keyPacked, countKey,
                                      histp, n);
    k_binscan<<<1, 64, 0, stream>>>(histp, cursor);
    k_scatter<<<nblk, 256, 0, stream>>>(keyPacked, cursor, binPts, n);
    k_scanblocks<<<KEYSPACE / 1024, 256, 0, stream>>>(countKey, psRank, bsums);
    k_scansums<<<1, 256, 0, stream>>>(bsums, boff, totals);
    k_fillseg<<<KEYSPACE / 256, 256, 0, stream>>>(countKey, psRank, boff, totals,
                                                  uniqKey, segStart, pointStart, n);
    int nbp = (npad + 255) / 256;
    if (big) {
        k_compute<<<nbp, 256, 0, stream>>>(binPts, feats, kern, pointStart,
                                           scratch, npad);
        int nthr = n * 4;
        k_reduce<<<(nthr + 255) / 256, 256, 0, stream>>>(scratch, segStart,
                                                         uniqKey, totals,
                                                         (float*)d_out,
                                                         (float*)d_out + (size_t)n * COUT,
                                                         n);
    } else {
        k_initout<<<2048, 256, 0, stream>>>((float4*)d_out, n * COUT / 4,
                                            n * (COUT + 4) / 4);
        k_computeA<<<nbp, 256, 0, stream>>>(binPts, feats, kern, psRank, boff,
                                            (float*)d_out,
                                            (float*)d_out + (size_t)n * COUT,
                                            npad);
    }
}